// Round 7
// baseline (130.674 us; speedup 1.0000x reference)
//
#include <hip/hip_runtime.h>
#include <cstdint>

#define NTOK 65536
#define DIM 240
#define KP 256
#define NMETA 600
#define NGB 512          // gating/permute blocks (128 tokens each)

typedef short bf16x8 __attribute__((ext_vector_type(8)));
typedef float f32x16 __attribute__((ext_vector_type(16)));

union U16B { uint4 u; bf16x8 v; };

__device__ __forceinline__ unsigned short f2bf(float x) {
  unsigned int u = __float_as_uint(x);
  u += 0x7fffu + ((u >> 16) & 1u);     // RNE
  return (unsigned short)(u >> 16);
}

// ---------------- kernel 1: pack expert weights to bf16 [8][256][256], bias fused at k=240
__global__ __launch_bounds__(256) void prep_w(const float* __restrict__ ew,
                                              const float* __restrict__ eb,
                                              unsigned short* __restrict__ Wb) {
  int idx = blockIdx.x * 256 + threadIdx.x;     // 131072 threads, 4 k's each
  int k0 = (idx & 63) << 2;
  int n  = (idx >> 6) & 255;
  int e  = idx >> 14;
  ushort4 v = {0, 0, 0, 0};
  if (n < DIM) {
    float f0 = 0.f, f1 = 0.f, f2 = 0.f, f3 = 0.f;
    const float* wrow = ew + (e * DIM + n) * DIM;
    if (k0 < DIM) { f0 = wrow[k0]; f1 = wrow[k0 + 1]; f2 = wrow[k0 + 2]; f3 = wrow[k0 + 3]; }
    else if (k0 == DIM) { f0 = eb[e * DIM + n]; }   // bias column
    v.x = f2bf(f0); v.y = f2bf(f1); v.z = f2bf(f2); v.w = f2bf(f3);
  }
  *(ushort4*)&Wb[(size_t)idx * 4] = v;
}

// ---------------- kernel 2: gating — pairid/wpair/per-block hist. NO global atomics.
__global__ __launch_bounds__(512) void gating(const float* __restrict__ x,
                                              const float* __restrict__ gw,
                                              const float* __restrict__ gb,
                                              unsigned char* __restrict__ pairid,
                                              float2* __restrict__ wpair,
                                              int* __restrict__ hist2d) {
  __shared__ __align__(16) float gwT[8][DIM];
  __shared__ int hist[64];
  for (int i = threadIdx.x; i < 8 * DIM; i += 512) gwT[i & 7][i >> 3] = gw[i];
  if (threadIdx.x < 64) hist[threadIdx.x] = 0;
  __syncthreads();
  const int lane = threadIdx.x & 63;
  const int w = threadIdx.x >> 6;
  const bool act = lane < 60;
  float4 g[8]; float gbv[8];
#pragma unroll
  for (int e = 0; e < 8; ++e) {
    g[e] = act ? *(const float4*)(&gwT[e][lane * 4]) : make_float4(0.f, 0.f, 0.f, 0.f);
    gbv[e] = gb[e];
  }
  const int tbase = blockIdx.x * 128 + w * 16;
  for (int it = 0; it < 16; ++it) {
    const int t = tbase + it;
    float4 xv = act ? *(const float4*)(x + (size_t)t * DIM + lane * 4)
                    : make_float4(0.f, 0.f, 0.f, 0.f);
    float p[8];
#pragma unroll
    for (int e = 0; e < 8; ++e)
      p[e] = xv.x * g[e].x + xv.y * g[e].y + xv.z * g[e].z + xv.w * g[e].w;
#pragma unroll
    for (int m = 1; m < 64; m <<= 1) {
#pragma unroll
      for (int e = 0; e < 8; ++e) p[e] += __shfl_xor(p[e], m, 64);
    }
    float l[8];
#pragma unroll
    for (int e = 0; e < 8; ++e) l[e] = p[e] + gbv[e];
    int i1 = 0; float b1 = l[0];
#pragma unroll
    for (int e = 1; e < 8; ++e) if (l[e] > b1) { b1 = l[e]; i1 = e; }
    int i2 = -1; float b2 = -3.0e38f;
#pragma unroll
    for (int e = 0; e < 8; ++e) if (e != i1 && l[e] > b2) { b2 = l[e]; i2 = e; }
    float q = expf(b2 - b1);
    float w1 = 1.f / (1.f + q);                  // weight of argmax
    float w2 = q / (1.f + q);                    // weight of runner-up
    if (lane == 0) {
      const int ea = (i1 < i2) ? i1 : i2, eb2 = (i1 < i2) ? i2 : i1;
      const float wa = (i1 < i2) ? w1 : w2, wb2 = (i1 < i2) ? w2 : w1;
      const int pp = ea * 8 + eb2;
      pairid[t] = (unsigned char)pp;
      wpair[t] = make_float2(wa, wb2);
      atomicAdd(&hist[pp], 1);                   // LDS only
    }
  }
  __syncthreads();
  if (threadIdx.x < 64) hist2d[blockIdx.x * 64 + threadIdx.x] = hist[threadIdx.x];
}

// ---------------- kernel 3: per-pair exclusive scan over 512 block-hists (64 blocks)
__global__ __launch_bounds__(512) void scan1_k(const int* __restrict__ hist2d,
                                               int* __restrict__ lbase2d,
                                               int* __restrict__ cnt) {
  __shared__ int s[NGB];
  const int p = blockIdx.x, tid = threadIdx.x;
  const int v = hist2d[tid * 64 + p];
  s[tid] = v;
  __syncthreads();
  for (int off = 1; off < NGB; off <<= 1) {
    int tv = (tid >= off) ? s[tid - off] : 0;
    __syncthreads();
    s[tid] += tv;
    __syncthreads();
  }
  lbase2d[tid * 64 + p] = s[tid] - v;            // exclusive within pair
  if (tid == NGB - 1) cnt[p] = s[tid];
}

// ---------------- kernel 4: pair starts + tile meta (1 block, 64 threads)
__global__ void scan2_k(const int* __restrict__ cnt, int* __restrict__ start,
                        int4* __restrict__ meta) {
  __shared__ int sc[64], sstart[64], stile[64], stot;
  const int tid = threadIdx.x;
  sc[tid] = cnt[tid];
  __syncthreads();
  if (tid == 0) {
    int a = 0, ta = 0;
    for (int p = 0; p < 64; ++p) { sstart[p] = a; stile[p] = ta; a += sc[p]; ta += (sc[p] + 255) >> 8; }
    stot = ta;
  }
  __syncthreads();
  start[tid] = sstart[tid];
  const int c = sc[tid], e0 = tid >> 3, e1 = tid & 7;
  for (int i = 0; (i << 8) < c; ++i)
    meta[stile[tid] + i] = make_int4(e0, e1, sstart[tid] + (i << 8), min(256, c - (i << 8)));
  for (int j = stot + tid; j < NMETA; j += 64)
    meta[j] = make_int4(0, 0, 0, 0);
}

// ---------------- kernel 5: permute + f32->bf16 pack: xbs[pos][256], wsorted, tokord
__global__ __launch_bounds__(512) void permute_k(const float* __restrict__ x,
                                                 const unsigned char* __restrict__ pairid,
                                                 const float2* __restrict__ wpair,
                                                 const int* __restrict__ start,
                                                 const int* __restrict__ lbase2d,
                                                 unsigned short* __restrict__ xbs,
                                                 float2* __restrict__ wsorted,
                                                 int* __restrict__ tokord) {
  __shared__ int lcnt[64], sp[128];
  const int b = blockIdx.x, tid = threadIdx.x;
  if (tid < 64) lcnt[tid] = 0;
  __syncthreads();
  if (tid < 128) {
    const int t = b * 128 + tid;
    const int p = pairid[t];
    const int rank = atomicAdd(&lcnt[p], 1);     // LDS only; intra-bucket order arbitrary
    const int pos = start[p] + lbase2d[b * 64 + p] + rank;
    sp[tid] = pos;
    wsorted[pos] = wpair[t];
    tokord[pos] = t;
  }
  __syncthreads();
  // copy/convert: 128 rows x 32 granules (granule = 8 bf16 = 16B out, 32B f32 in)
  for (int j = tid; j < 128 * 32; j += 512) {
    const int tl = j >> 5, og = j & 31;
    const size_t src = (size_t)(b * 128 + tl) * DIM + og * 8;
    ushort4 o0 = {0, 0, 0, 0}, o1 = {0, 0, 0, 0};
    if (og < 30) {
      const float4 q0 = *(const float4*)(x + src);
      const float4 q1 = *(const float4*)(x + src + 4);
      o0.x = f2bf(q0.x); o0.y = f2bf(q0.y); o0.z = f2bf(q0.z); o0.w = f2bf(q0.w);
      o1.x = f2bf(q1.x); o1.y = f2bf(q1.y); o1.z = f2bf(q1.z); o1.w = f2bf(q1.w);
    } else if (og == 30) {
      o0.x = 0x3F80;                             // k=240 bias column = 1.0
    }
    unsigned short* dst = xbs + (size_t)sp[tl] * KP + og * 8;
    *(ushort4*)dst = o0;
    *(ushort4*)(dst + 4) = o1;
  }
}

// ---------------- kernel 6: pair-sparse GEMM, 256 tok x 256 col, BK=32, 2 blocks/CU
#define GLDS16(g, l)                                                        \
  __builtin_amdgcn_global_load_lds(                                         \
      (__attribute__((address_space(1))) unsigned int*)(g),                 \
      (__attribute__((address_space(3))) unsigned int*)(l), 16, 0, 0)

// stage a [256 rows][32 k] bf16 chunk (16KB) from a 512B-stride row-major source.
// linear layout (row = 64B); kc = 64B K-offset index.
__device__ __forceinline__ void stage16k(const char* gbase, char* lds, int kc, int tid) {
#pragma unroll
  for (int j = 0; j < 2; ++j) {
    const int o = tid * 16 + j * 8192;
    const int r = o >> 6, b = o & 63;
    GLDS16(gbase + (size_t)r * 512 + kc * 64 + b, lds + o);
  }
}

__global__ __launch_bounds__(512, 2) void moe_gemm_pair(const unsigned short* __restrict__ xbs,
                                                        const unsigned short* __restrict__ Wb,
                                                        const float2* __restrict__ wsorted,
                                                        const int* __restrict__ tokord,
                                                        const int4* __restrict__ meta,
                                                        float* __restrict__ out) {
  extern __shared__ __align__(16) char smem[];
  // [0,32K): A dbuf 2x16K  [32K,64K): W dbuf 2x16K  [64K..]: ptok[256], wab[256]
  int* ptok = (int*)(smem + 65536);
  float2* wab = (float2*)(smem + 66560);

  const int4 m = meta[blockIdx.x];
  const int n = m.w;
  if (n == 0) return;
  const int tid = threadIdx.x, lane = tid & 63, wid = tid >> 6;
  const int wr = wid >> 2, wc = wid & 3;         // 2 row-waves x 4 col-waves, wave 128x64
  const int l31 = lane & 31, hi = lane >> 5;

  if (tid < 256) {
    ptok[tid] = tokord[m.z + tid];
    const float2 w2 = wsorted[m.z + tid];
    const float wbg = fmaxf(w2.y, 1e-35f);
    wab[tid] = make_float2(w2.x / wbg, wbg);     // (ratio wA/wBg, final scale wBg)
  }

  const char* abase = (const char*)xbs + (size_t)m.z * 512;
  const char* wbase0 = (const char*)Wb + (size_t)m.x * 131072;
  const char* wbase1 = (const char*)Wb + (size_t)m.y * 131072;

  // prologue: it=0 (A kc0, W expert m.x kc0) -> buffer 0
  stage16k(abase, smem, 0, tid);
  stage16k(wbase0, smem + 32768, 0, tid);
  __syncthreads();

  f32x16 acc[4][2] = {};

  for (int it = 0; it < 16; ++it) {              // it = pass*8 + kc; pass0 -> m.x, pass1 -> m.y
    const int buf = it & 1;
    if (it < 15) {                               // prefetch next chunk into other buffer
      const int nx = it + 1;
      const int kc = nx & 7;
      const char* wb = (nx >> 3) ? wbase1 : wbase0;
      stage16k(abase, smem + ((buf ^ 1) << 14), kc, tid);
      stage16k(wb, smem + 32768 + ((buf ^ 1) << 14), kc, tid);
    }
    if (it == 8) {                               // acc = P_A complete -> scale by wA/wBg
#pragma unroll
      for (int af = 0; af < 4; ++af) {
#pragma unroll
        for (int r = 0; r < 16; ++r) {
          const int rw = wr * 128 + af * 32 + (r & 3) + ((r >> 2) << 3) + (hi << 2);
          const float s = wab[rw].x;
          acc[af][0][r] *= s;
          acc[af][1][r] *= s;
        }
      }
    }
    const char* Ab = smem + (buf << 14);
    const char* Wp = smem + 32768 + (buf << 14);
#pragma unroll
    for (int ks = 0; ks < 2; ++ks) {
      const int sx = ks * 32 + (hi << 4);
      U16B a0, a1, a2, a3, b0, b1;
      a0.u = *(const uint4*)(Ab + (wr * 128 +  0 + l31) * 64 + sx);
      a1.u = *(const uint4*)(Ab + (wr * 128 + 32 + l31) * 64 + sx);
      a2.u = *(const uint4*)(Ab + (wr * 128 + 64 + l31) * 64 + sx);
      a3.u = *(const uint4*)(Ab + (wr * 128 + 96 + l31) * 64 + sx);
      b0.u = *(const uint4*)(Wp + (wc * 64 +  0 + l31) * 64 + sx);
      b1.u = *(const uint4*)(Wp + (wc * 64 + 32 + l31) * 64 + sx);
      acc[0][0] = __builtin_amdgcn_mfma_f32_32x32x16_bf16(a0.v, b0.v, acc[0][0], 0, 0, 0);
      acc[0][1] = __builtin_amdgcn_mfma_f32_32x32x16_bf16(a0.v, b1.v, acc[0][1], 0, 0, 0);
      acc[1][0] = __builtin_amdgcn_mfma_f32_32x32x16_bf16(a1.v, b0.v, acc[1][0], 0, 0, 0);
      acc[1][1] = __builtin_amdgcn_mfma_f32_32x32x16_bf16(a1.v, b1.v, acc[1][1], 0, 0, 0);
      acc[2][0] = __builtin_amdgcn_mfma_f32_32x32x16_bf16(a2.v, b0.v, acc[2][0], 0, 0, 0);
      acc[2][1] = __builtin_amdgcn_mfma_f32_32x32x16_bf16(a2.v, b1.v, acc[2][1], 0, 0, 0);
      acc[3][0] = __builtin_amdgcn_mfma_f32_32x32x16_bf16(a3.v, b0.v, acc[3][0], 0, 0, 0);
      acc[3][1] = __builtin_amdgcn_mfma_f32_32x32x16_bf16(a3.v, b1.v, acc[3][1], 0, 0, 0);
    }
    __syncthreads();     // prefetch drained + bufs released; 2nd resident block covers the stall
  }

  // epilogue: out[tok, col] = wBg * acc
#pragma unroll
  for (int af = 0; af < 4; ++af) {
#pragma unroll
    for (int bf = 0; bf < 2; ++bf) {
      const int col = wc * 64 + bf * 32 + l31;
      if (col < DIM) {
#pragma unroll
        for (int r = 0; r < 16; ++r) {
          const int rw = wr * 128 + af * 32 + (r & 3) + ((r >> 2) << 3) + (hi << 2);
          if (rw < n) out[(size_t)ptok[rw] * DIM + col] = wab[rw].y * acc[af][bf][r];
        }
      }
    }
  }
}

extern "C" void kernel_launch(void* const* d_in, const int* in_sizes, int n_in,
                              void* d_out, int out_size, void* d_ws, size_t ws_size,
                              hipStream_t stream) {
  const float* x  = (const float*)d_in[0];
  const float* gw = (const float*)d_in[1];
  const float* gb = (const float*)d_in[2];
  const float* ew = (const float*)d_in[3];
  const float* eb = (const float*)d_in[4];
  float* out = (float*)d_out;

  // workspace layout (~36.4 MB total)
  char* ws = (char*)d_ws;
  unsigned short* Wb   = (unsigned short*)ws;                          // 1 MB
  unsigned short* xbs  = (unsigned short*)(ws + 1048576);              // (65536+256)*512B
  float2*         wpr  = (float2*)(ws + 34734080);                     // 512 KB
  float2*         wsr  = (float2*)(ws + 35258368);                     // (65536+256)*8B
  int*            tord = (int*)(ws + 35784704);                        // (65536+256)*4B
  unsigned char*  pid  = (unsigned char*)(ws + 36047872);              // 64 KB
  int*            h2d  = (int*)(ws + 36113408);                        // 128 KB
  int*            lb2d = (int*)(ws + 36244480);                        // 128 KB
  int*            cnt  = (int*)(ws + 36375552);                        // 256 B
  int*            strt = (int*)(ws + 36375808);                        // 256 B
  int4*           meta = (int4*)(ws + 36376064);                       // 9.6 KB

  hipFuncSetAttribute((const void*)moe_gemm_pair, hipFuncAttributeMaxDynamicSharedMemorySize, 68608);

  prep_w<<<512, 256, 0, stream>>>(ew, eb, Wb);
  gating<<<NGB, 512, 0, stream>>>(x, gw, gb, pid, wpr, h2d);
  scan1_k<<<64, NGB, 0, stream>>>(h2d, lb2d, cnt);
  scan2_k<<<1, 64, 0, stream>>>(cnt, strt, meta);
  permute_k<<<NGB, 512, 0, stream>>>(x, pid, wpr, strt, lb2d, xbs, wsr, tord);
  moe_gemm_pair<<<NMETA, 512, 68608, stream>>>(xbs, Wb, wsr, tord, meta, out);
}

// Round 8
// 120.282 us; speedup vs baseline: 1.0864x; 1.0864x over previous
//
#include <hip/hip_runtime.h>
#include <cstdint>

#define NTOK 65536
#define DIM 240
#define KP 256
#define NMETA 576
#define NGB 512          // gating blocks (128 tokens each)

typedef short bf16x8 __attribute__((ext_vector_type(8)));
typedef float f32x16 __attribute__((ext_vector_type(16)));

union U16B { uint4 u; bf16x8 v; };

__device__ __forceinline__ unsigned short f2bf(float x) {
  unsigned int u = __float_as_uint(x);
  u += 0x7fffu + ((u >> 16) & 1u);     // RNE
  return (unsigned short)(u >> 16);
}

// ---------------- kernel 1: pack expert weights to bf16 [8][256][256], bias fused at k=240
__global__ __launch_bounds__(256) void prep_w(const float* __restrict__ ew,
                                              const float* __restrict__ eb,
                                              unsigned short* __restrict__ Wb) {
  int idx = blockIdx.x * 256 + threadIdx.x;     // 131072 threads, 4 k's each
  int k0 = (idx & 63) << 2;
  int n  = (idx >> 6) & 255;
  int e  = idx >> 14;
  ushort4 v = {0, 0, 0, 0};
  if (n < DIM) {
    float f0 = 0.f, f1 = 0.f, f2 = 0.f, f3 = 0.f;
    const float* wrow = ew + (e * DIM + n) * DIM;
    if (k0 < DIM) { f0 = wrow[k0]; f1 = wrow[k0 + 1]; f2 = wrow[k0 + 2]; f3 = wrow[k0 + 3]; }
    else if (k0 == DIM) { f0 = eb[e * DIM + n]; }   // bias column
    v.x = f2bf(f0); v.y = f2bf(f1); v.z = f2bf(f2); v.w = f2bf(f3);
  }
  *(ushort4*)&Wb[(size_t)idx * 4] = v;
}

// ---------------- kernel 2: gating + unsorted bf16 activations xb[t][256] + pair id/hist
__global__ __launch_bounds__(512) void gating(const float* __restrict__ x,
                                              const float* __restrict__ gw,
                                              const float* __restrict__ gb,
                                              unsigned short* __restrict__ xb,
                                              unsigned char* __restrict__ pairid,
                                              float2* __restrict__ wpair,
                                              int* __restrict__ hist2d) {
  __shared__ __align__(16) float gwT[8][DIM];
  __shared__ int hist[64];
  for (int i = threadIdx.x; i < 8 * DIM; i += 512) gwT[i & 7][i >> 3] = gw[i];
  if (threadIdx.x < 64) hist[threadIdx.x] = 0;
  __syncthreads();
  const int lane = threadIdx.x & 63;
  const int w = threadIdx.x >> 6;
  const bool act = lane < 60;
  float4 g[8]; float gbv[8];
#pragma unroll
  for (int e = 0; e < 8; ++e) {
    g[e] = act ? *(const float4*)(&gwT[e][lane * 4]) : make_float4(0.f, 0.f, 0.f, 0.f);
    gbv[e] = gb[e];
  }
  const int tbase = blockIdx.x * 128 + w * 16;
  for (int it = 0; it < 16; ++it) {
    const int t = tbase + it;
    float4 xv = act ? *(const float4*)(x + (size_t)t * DIM + lane * 4)
                    : make_float4(0.f, 0.f, 0.f, 0.f);
    float p[8];
#pragma unroll
    for (int e = 0; e < 8; ++e)
      p[e] = xv.x * g[e].x + xv.y * g[e].y + xv.z * g[e].z + xv.w * g[e].w;
#pragma unroll
    for (int m = 1; m < 64; m <<= 1) {
#pragma unroll
      for (int e = 0; e < 8; ++e) p[e] += __shfl_xor(p[e], m, 64);
    }
    float l[8];
#pragma unroll
    for (int e = 0; e < 8; ++e) l[e] = p[e] + gbv[e];
    int i1 = 0; float b1 = l[0];
#pragma unroll
    for (int e = 1; e < 8; ++e) if (l[e] > b1) { b1 = l[e]; i1 = e; }
    int i2 = -1; float b2 = -3.0e38f;
#pragma unroll
    for (int e = 0; e < 8; ++e) if (e != i1 && l[e] > b2) { b2 = l[e]; i2 = e; }
    float q = expf(b2 - b1);
    float w1 = 1.f / (1.f + q);                  // weight of argmax
    float w2 = q / (1.f + q);                    // weight of runner-up
    ushort4 v = {0, 0, 0, 0};
    if (act) { v.x = f2bf(xv.x); v.y = f2bf(xv.y); v.z = f2bf(xv.z); v.w = f2bf(xv.w); }
    else if (lane == 60) v.x = 0x3F80;           // x[240] = 1.0 (bias column)
    *(ushort4*)(xb + (size_t)t * KP + lane * 4) = v;
    if (lane == 0) {
      const int ea = (i1 < i2) ? i1 : i2, eb2 = (i1 < i2) ? i2 : i1;
      const float wa = (i1 < i2) ? w1 : w2, wb2 = (i1 < i2) ? w2 : w1;
      const int pp = ea * 8 + eb2;
      pairid[t] = (unsigned char)pp;
      wpair[t] = make_float2(wa, wb2);
      atomicAdd(&hist[pp], 1);                   // LDS only
    }
  }
  __syncthreads();
  if (threadIdx.x < 64) hist2d[blockIdx.x * 64 + threadIdx.x] = hist[threadIdx.x];
}

// ---------------- kernel 3: per-pair exclusive scan over 512 block-hists (64 blocks)
__global__ __launch_bounds__(512) void scan1_k(const int* __restrict__ hist2d,
                                               int* __restrict__ lbase2d,
                                               int* __restrict__ cnt) {
  __shared__ int s[NGB];
  const int p = blockIdx.x, tid = threadIdx.x;
  const int v = hist2d[tid * 64 + p];
  s[tid] = v;
  __syncthreads();
  for (int off = 1; off < NGB; off <<= 1) {
    int tv = (tid >= off) ? s[tid - off] : 0;
    __syncthreads();
    s[tid] += tv;
    __syncthreads();
  }
  lbase2d[tid * 64 + p] = s[tid] - v;            // exclusive within pair
  if (tid == NGB - 1) cnt[p] = s[tid];
}

// ---------------- kernel 4: pair starts + tile meta (128-token tiles; 1 block, 64 threads)
__global__ void scan2_k(const int* __restrict__ cnt, int* __restrict__ start,
                        int4* __restrict__ meta) {
  __shared__ int sc[64], sstart[64], stile[64], stot;
  const int tid = threadIdx.x;
  sc[tid] = cnt[tid];
  __syncthreads();
  if (tid == 0) {
    int a = 0, ta = 0;
    for (int p = 0; p < 64; ++p) { sstart[p] = a; stile[p] = ta; a += sc[p]; ta += (sc[p] + 127) >> 7; }
    stot = ta;
  }
  __syncthreads();
  start[tid] = sstart[tid];
  const int c = sc[tid], e0 = tid >> 3, e1 = tid & 7;
  for (int i = 0; (i << 7) < c; ++i)
    meta[stile[tid] + i] = make_int4(e0, e1, sstart[tid] + (i << 7), min(128, c - (i << 7)));
  for (int j = stot + tid; j < NMETA; j += 64)
    meta[j] = make_int4(0, 0, 0, 0);
}

// ---------------- kernel 5: route only (no data copy): wsorted/tokord
__global__ __launch_bounds__(128) void route_k(const unsigned char* __restrict__ pairid,
                                               const float2* __restrict__ wpair,
                                               const int* __restrict__ start,
                                               const int* __restrict__ lbase2d,
                                               float2* __restrict__ wsorted,
                                               int* __restrict__ tokord) {
  __shared__ int lcnt[64];
  const int b = blockIdx.x, tid = threadIdx.x;
  if (tid < 64) lcnt[tid] = 0;
  __syncthreads();
  const int t = b * 128 + tid;
  const int p = pairid[t];
  const int rank = atomicAdd(&lcnt[p], 1);       // LDS only
  const int pos = start[p] + lbase2d[b * 64 + p] + rank;
  wsorted[pos] = wpair[t];
  tokord[pos] = t;
}

// ---------------- kernel 6: pair-sparse GEMM, 128 tok x 128 col, granule-major LDS,
//                  gathered A (per-lane global_load_lds sources), 4 blocks/CU
#define GLDS16(g, l)                                                        \
  __builtin_amdgcn_global_load_lds(                                         \
      (__attribute__((address_space(1))) unsigned int*)(g),                 \
      (__attribute__((address_space(3))) unsigned int*)(l), 16, 0, 0)

__global__ __launch_bounds__(256, 4) void moe_gemm_pair(const unsigned short* __restrict__ xb,
                                                        const unsigned short* __restrict__ Wb,
                                                        const float2* __restrict__ wsorted,
                                                        const int* __restrict__ tokord,
                                                        const int4* __restrict__ meta,
                                                        float* __restrict__ out) {
  extern __shared__ __align__(16) char smem[];
  // [0,16K): A dbuf 2x8K  [16K,32K): W dbuf 2x8K   layout: [granule(4)][row(128)][16B]
  // [32K,+512): ptok   [32.5K,+1K): wab
  int* ptok = (int*)(smem + 32768);
  float2* wab = (float2*)(smem + 33280);

  const int4 m = meta[blockIdx.x >> 1];
  const int n = m.w;
  if (n == 0) return;
  const int ch = blockIdx.x & 1;                 // column half: cols [ch*128, ch*128+128)
  const int tid = threadIdx.x, lane = tid & 63, wid = tid >> 6;
  const int wr = wid >> 1, wc = wid & 1;         // 2x2 wave grid, wave tile 64x64
  const int l31 = lane & 31, hi = lane >> 5;

  if (tid < 128) {
    const int idx = m.z + (tid < n ? tid : n - 1);
    ptok[tid] = tokord[idx];
    const float2 w2 = wsorted[idx];
    const float wbg = fmaxf(w2.y, 1e-35f);
    wab[tid] = make_float2(w2.x / wbg, wbg);     // (ratio wA/wBg, final scale wBg)
  }
  __syncthreads();

  // staging geometry: thread covers (granule g0 and g0+2) of row srow.
  // LDS dest linear (tid*16 / tid*16+4096); global source per-lane (gather OK).
  const int srow = tid & 127;
  const int g0 = tid >> 7;                       // 0 or 1
  const char* asrc = (const char*)xb + (size_t)ptok[srow] * 512 + g0 * 16;
  const int wsoff = (ch * 128 + srow) * 512 + g0 * 16;
  const char* wb0 = (const char*)Wb + (size_t)m.x * 131072;
  const char* wb1 = (const char*)Wb + (size_t)m.y * 131072;

#define STAGE(B, KC, WBE) do {                                   \
    char* Ad = smem + ((B) << 13) + tid * 16;                    \
    char* Wd = smem + 16384 + ((B) << 13) + tid * 16;            \
    GLDS16(asrc + (KC) * 64, Ad);                                \
    GLDS16(asrc + (KC) * 64 + 32, Ad + 4096);                    \
    GLDS16((WBE) + wsoff + (KC) * 64, Wd);                       \
    GLDS16((WBE) + wsoff + (KC) * 64 + 32, Wd + 4096);           \
  } while (0)

  // prologue: it=0 (expert m.x, kc=0) -> buffer 0
  STAGE(0, 0, wb0);
  __syncthreads();

  f32x16 acc[2][2] = {};

  for (int it = 0; it < 16; ++it) {              // it = pass*8 + kc; pass0 -> m.x, pass1 -> m.y
    const int buf = it & 1;
    if (it < 15) {                               // prefetch next chunk into other buffer
      const int nx = it + 1;
      STAGE(buf ^ 1, nx & 7, (nx >> 3) ? wb1 : wb0);
    }
    if (it == 8) {                               // acc = P_A complete -> scale by wA/wBg
#pragma unroll
      for (int af = 0; af < 2; ++af) {
#pragma unroll
        for (int r = 0; r < 16; ++r) {
          const int rw = wr * 64 + af * 32 + (r & 3) + ((r >> 2) << 3) + (hi << 2);
          const float s = wab[rw].x;
          acc[af][0][r] *= s;
          acc[af][1][r] *= s;
        }
      }
    }
    const char* Ab = smem + (buf << 13);
    const char* Wp = smem + 16384 + (buf << 13);
#pragma unroll
    for (int ks = 0; ks < 2; ++ks) {
      const int go = (ks * 2 + hi) << 11;        // granule offset (k = ks*16 + hi*8)
      U16B a0, a1, b0, b1;
      a0.u = *(const uint4*)(Ab + go + ((wr * 64 +  0 + l31) << 4));
      a1.u = *(const uint4*)(Ab + go + ((wr * 64 + 32 + l31) << 4));
      b0.u = *(const uint4*)(Wp + go + ((wc * 64 +  0 + l31) << 4));
      b1.u = *(const uint4*)(Wp + go + ((wc * 64 + 32 + l31) << 4));
      acc[0][0] = __builtin_amdgcn_mfma_f32_32x32x16_bf16(a0.v, b0.v, acc[0][0], 0, 0, 0);
      acc[0][1] = __builtin_amdgcn_mfma_f32_32x32x16_bf16(a0.v, b1.v, acc[0][1], 0, 0, 0);
      acc[1][0] = __builtin_amdgcn_mfma_f32_32x32x16_bf16(a1.v, b0.v, acc[1][0], 0, 0, 0);
      acc[1][1] = __builtin_amdgcn_mfma_f32_32x32x16_bf16(a1.v, b1.v, acc[1][1], 0, 0, 0);
    }
    __syncthreads();     // prefetch drained + bufs released; 3 other resident blocks cover stall
  }

  // epilogue: out[tok, col] = wBg * acc
#pragma unroll
  for (int af = 0; af < 2; ++af) {
#pragma unroll
    for (int bf = 0; bf < 2; ++bf) {
      const int col = ch * 128 + wc * 64 + bf * 32 + l31;
      if (col < DIM) {
#pragma unroll
        for (int r = 0; r < 16; ++r) {
          const int rw = wr * 64 + af * 32 + (r & 3) + ((r >> 2) << 3) + (hi << 2);
          if (rw < n) out[(size_t)ptok[rw] * DIM + col] = wab[rw].y * acc[af][bf][r];
        }
      }
    }
  }
#undef STAGE
}

extern "C" void kernel_launch(void* const* d_in, const int* in_sizes, int n_in,
                              void* d_out, int out_size, void* d_ws, size_t ws_size,
                              hipStream_t stream) {
  const float* x  = (const float*)d_in[0];
  const float* gw = (const float*)d_in[1];
  const float* gb = (const float*)d_in[2];
  const float* ew = (const float*)d_in[3];
  const float* eb = (const float*)d_in[4];
  float* out = (float*)d_out;

  // workspace layout (~36.3 MB)
  char* ws = (char*)d_ws;
  unsigned short* Wb   = (unsigned short*)ws;                          // 1 MB
  unsigned short* xb   = (unsigned short*)(ws + 1048576);              // 32 MB (unsorted bf16 [NTOK][256])
  float2*         wpr  = (float2*)(ws + 34603008);                     // 512 KB
  float2*         wsr  = (float2*)(ws + 35127296);                     // 512 KB
  int*            tord = (int*)(ws + 35651584);                        // 256 KB
  unsigned char*  pid  = (unsigned char*)(ws + 35913728);              // 64 KB
  int*            h2d  = (int*)(ws + 35979264);                        // 128 KB
  int*            lb2d = (int*)(ws + 36110336);                        // 128 KB
  int*            cnt  = (int*)(ws + 36241408);                        // 256 B
  int*            strt = (int*)(ws + 36241664);                        // 256 B
  int4*           meta = (int4*)(ws + 36241920);                       // 9.2 KB

  hipFuncSetAttribute((const void*)moe_gemm_pair, hipFuncAttributeMaxDynamicSharedMemorySize, 34304);

  prep_w<<<512, 256, 0, stream>>>(ew, eb, Wb);
  gating<<<NGB, 512, 0, stream>>>(x, gw, gb, xb, pid, wpr, h2d);
  scan1_k<<<64, NGB, 0, stream>>>(h2d, lb2d, cnt);
  scan2_k<<<1, 64, 0, stream>>>(cnt, strt, meta);
  route_k<<<NGB, 128, 0, stream>>>(pid, wpr, strt, lb2d, wsr, tord);
  moe_gemm_pair<<<2 * NMETA, 256, 34304, stream>>>(xb, Wb, wsr, tord, meta, out);
}